// Round 1
// baseline (218.975 us; speedup 1.0000x reference)
//
#include <hip/hip_runtime.h>
#include <stdint.h>

typedef __bf16 bf16_t;
typedef __bf16 bf16x8 __attribute__((ext_vector_type(8)));
typedef __bf16 bf16x4 __attribute__((ext_vector_type(4)));
typedef float  f32x4  __attribute__((ext_vector_type(4)));

// ---------- helpers ----------

__device__ __forceinline__ void gload16(const void* g, void* lds)
{
    // global -> LDS direct copy, 16 B per lane; LDS dest must be wave-uniform,
    // HW appends lane*16.
    __builtin_amdgcn_global_load_lds(
        (__attribute__((address_space(1))) void*)(void*)g,
        (__attribute__((address_space(3))) void*)lds,
        16, 0, 0);
}

__device__ __forceinline__ f32x4 mfma16(bf16x8 a, bf16x8 b, f32x4 c)
{
    return __builtin_amdgcn_mfma_f32_16x16x32_bf16(a, b, c, 0, 0, 0);
}

// ---------- prep kernels ----------

// flat f32 -> bf16 cast, 4 elems/thread, exact sizing
__global__ __launch_bounds__(256)
void cast_f32_bf16(const float* __restrict__ in, bf16_t* __restrict__ out, int n4)
{
    const int i = blockIdx.x * blockDim.x + threadIdx.x;
    if (i >= n4) return;
    float4 f = *(const float4*)&in[(size_t)i * 4];
    bf16x4 o;
    o[0] = (bf16_t)f.x; o[1] = (bf16_t)f.y; o[2] = (bf16_t)f.z; o[3] = (bf16_t)f.w;
    *(bf16x4*)&out[(size_t)i * 4] = o;
}

// gather even tokens within each segment, cast to bf16.
// m = b*2048 + g*256 + j  ->  src row = b*4096 + g*512 + 2j
__global__ __launch_bounds__(256)
void gather_cast_x(const float* __restrict__ x, bf16_t* __restrict__ Xe)
{
    const int m = blockIdx.x;
    const int b = m >> 11, g = (m >> 8) & 7, j = m & 255;
    const float* src = x + ((size_t)b * 4096 + g * 512 + 2 * j) * 1024;
    bf16_t* dst = Xe + (size_t)m * 1024;
    const int t = threadIdx.x;
    float4 f = *(const float4*)&src[t * 4];
    bf16x4 o;
    o[0] = (bf16_t)f.x; o[1] = (bf16_t)f.y; o[2] = (bf16_t)f.z; o[3] = (bf16_t)f.w;
    *(bf16x4*)&dst[t * 4] = o;
}

// ---------- GEMM: C[M,N] = A[M,K] * B[N,K]^T (both K-major, bf16, fp32 acc) ----------
// 128x128 tile, BK=32, 256 threads = 4 waves (2x2), 16x16x32 MFMA, m97 structure.
// EPI: 0 = store bf16, 1 = store f32, 2 = scatter f32 into d_out even rows.
template<int EPI>
__global__ __launch_bounds__(256)
void gemm_nt(const bf16_t* __restrict__ A, const bf16_t* __restrict__ B,
             void* __restrict__ Cv,
             int K, int lda, int ldb, int ldc,
             long sA, long sB, long sC)
{
    __shared__ __align__(16) bf16_t Asm[128 * 32];
    __shared__ __align__(16) bf16_t Bsm[128 * 32];

    const int tid  = threadIdx.x;
    const int wave = tid >> 6;
    const int lane = tid & 63;
    const int bn = blockIdx.x, bm = blockIdx.y, bz = blockIdx.z;
    const int wr = wave >> 1, wc = wave & 1;

    const bf16_t* Ab = A + (long)bz * sA;
    const bf16_t* Bb = B + (long)bz * sB;

    // staging: tile row = tid/4 (+64 for second call), col = (tid%4)*8
    const int srow = tid >> 2;
    const int scol = (tid & 3) * 8;
    const bf16_t* a0 = Ab + (size_t)(bm * 128 + srow) * lda + scol;
    const bf16_t* a1 = a0 + (size_t)64 * lda;
    const bf16_t* b0 = Bb + (size_t)(bn * 128 + srow) * ldb + scol;
    const bf16_t* b1 = b0 + (size_t)64 * ldb;
    char* ldsA = (char*)Asm + wave * 1024;   // wave-uniform dest
    char* ldsB = (char*)Bsm + wave * 1024;

    f32x4 acc[4][4] = {};

    const int frow = lane & 15;          // fragment row (A) / col (B)
    const int fk   = (lane >> 4) * 8;    // k-slice within BK=32

    for (int k0 = 0; k0 < K; k0 += 32) {
        gload16(a0, ldsA);
        gload16(a1, ldsA + 4096);
        gload16(b0, ldsB);
        gload16(b1, ldsB + 4096);
        a0 += 32; a1 += 32; b0 += 32; b1 += 32;
        __syncthreads();   // drains vmcnt -> LDS tile ready

        bf16x8 af[4], bfr[4];
#pragma unroll
        for (int mi = 0; mi < 4; ++mi)
            af[mi] = *(const bf16x8*)&Asm[(size_t)(wr * 64 + mi * 16 + frow) * 32 + fk];
#pragma unroll
        for (int ni = 0; ni < 4; ++ni)
            bfr[ni] = *(const bf16x8*)&Bsm[(size_t)(wc * 64 + ni * 16 + frow) * 32 + fk];
#pragma unroll
        for (int mi = 0; mi < 4; ++mi)
#pragma unroll
            for (int ni = 0; ni < 4; ++ni)
                acc[mi][ni] = mfma16(af[mi], bfr[ni], acc[mi][ni]);
        __syncthreads();   // protect LDS before next stage
    }

    // C/D layout: col = lane&15, row = (lane>>4)*4 + r  [m89/m91 verified]
    const int row0 = bm * 128 + wr * 64 + (lane >> 4) * 4;
    const int col0 = bn * 128 + wc * 64 + frow;

    if constexpr (EPI == 0) {
        bf16_t* C = (bf16_t*)Cv + (long)bz * sC;
#pragma unroll
        for (int mi = 0; mi < 4; ++mi)
#pragma unroll
            for (int ni = 0; ni < 4; ++ni)
#pragma unroll
                for (int r = 0; r < 4; ++r)
                    C[(size_t)(row0 + mi * 16 + r) * ldc + col0 + ni * 16] =
                        (bf16_t)acc[mi][ni][r];
    } else if constexpr (EPI == 1) {
        float* C = (float*)Cv + (long)bz * sC;
#pragma unroll
        for (int mi = 0; mi < 4; ++mi)
#pragma unroll
            for (int ni = 0; ni < 4; ++ni)
#pragma unroll
                for (int r = 0; r < 4; ++r)
                    C[(size_t)(row0 + mi * 16 + r) * ldc + col0 + ni * 16] =
                        acc[mi][ni][r];
    } else {
        // scatter: m -> global row b*4096 + g*512 + 2j (odd rows stay zero)
        float* C = (float*)Cv;
#pragma unroll
        for (int mi = 0; mi < 4; ++mi)
#pragma unroll
            for (int ni = 0; ni < 4; ++ni)
#pragma unroll
                for (int r = 0; r < 4; ++r) {
                    const int m  = row0 + mi * 16 + r;
                    const int gr = ((m >> 11) << 12) | (((m >> 8) & 7) << 9) | ((m & 255) << 1);
                    C[(size_t)gr * 1024 + col0 + ni * 16] = acc[mi][ni][r];
                }
    }
}

// ---------- LayerNorm (in place on bf16 QKV rows, D=1024) ----------
__global__ __launch_bounds__(256)
void ln_kernel(bf16_t* __restrict__ qkv,
               const float* __restrict__ gamma, const float* __restrict__ beta)
{
    const int row = blockIdx.x;       // 0..8191
    const int which = blockIdx.y;     // 0=q 1=k 2=v
    bf16_t* p = qkv + (size_t)row * 3072 + which * 1024;
    const int t = threadIdx.x;

    bf16x4 v = *(const bf16x4*)&p[t * 4];
    float f[4];
    float s = 0.f, ss = 0.f;
#pragma unroll
    for (int i = 0; i < 4; ++i) { f[i] = (float)v[i]; s += f[i]; ss += f[i] * f[i]; }
#pragma unroll
    for (int o = 32; o; o >>= 1) { s += __shfl_xor(s, o); ss += __shfl_xor(ss, o); }

    __shared__ float rs_[4], rss_[4];
    const int wave = t >> 6, lane = t & 63;
    if (lane == 0) { rs_[wave] = s; rss_[wave] = ss; }
    __syncthreads();
    s  = rs_[0] + rs_[1] + rs_[2] + rs_[3];
    ss = rss_[0] + rss_[1] + rss_[2] + rss_[3];

    const float mu   = s * (1.f / 1024.f);
    const float var  = ss * (1.f / 1024.f) - mu * mu;
    const float rstd = rsqrtf(var + 1e-5f);

    bf16x4 o;
#pragma unroll
    for (int i = 0; i < 4; ++i) {
        const int c = t * 4 + i;
        o[i] = (bf16_t)((f[i] - mu) * rstd * gamma[c] + beta[c]);
    }
    *(bf16x4*)&p[t * 4] = o;
}

// ---------- causal softmax: S[32*256][256] f32 -> P bf16 ----------
__global__ __launch_bounds__(256)
void softmax_kernel(const float* __restrict__ S, bf16_t* __restrict__ P)
{
    const int q = blockIdx.x & 255;
    const size_t base = (size_t)blockIdx.x * 256;
    const int c = threadIdx.x;
    const bool ok = (c <= q);

    float v = ok ? S[base + c] * (1.f / 32.f) : -3.0e38f;
    float m = v;
#pragma unroll
    for (int o = 32; o; o >>= 1) m = fmaxf(m, __shfl_xor(m, o));

    __shared__ float rm[4], rsum[4];
    const int wave = c >> 6, lane = c & 63;
    if (lane == 0) rm[wave] = m;
    __syncthreads();
    m = fmaxf(fmaxf(rm[0], rm[1]), fmaxf(rm[2], rm[3]));

    float e = ok ? __expf(v - m) : 0.f;
    float s = e;
#pragma unroll
    for (int o = 32; o; o >>= 1) s += __shfl_xor(s, o);
    if (lane == 0) rsum[wave] = s;
    __syncthreads();
    s = rsum[0] + rsum[1] + rsum[2] + rsum[3];

    P[base + c] = (bf16_t)(e / s);
}

// ---------- V transpose per segment: Vn[k][e] (stride 3072) -> Vt[seg][e][k] ----------
__global__ __launch_bounds__(256)
void transpose_v(const bf16_t* __restrict__ Vn, bf16_t* __restrict__ Vt)
{
    __shared__ bf16_t tile[32][33];
    const int seg = blockIdx.z;
    const int e0 = blockIdx.x * 32, k0 = blockIdx.y * 32;
    const int xx = threadIdx.x, yy = threadIdx.y;
    const bf16_t* src = Vn + (size_t)seg * 256 * 3072;
#pragma unroll
    for (int i = 0; i < 32; i += 8)
        tile[yy + i][xx] = src[(size_t)(k0 + yy + i) * 3072 + e0 + xx];
    __syncthreads();
    bf16_t* dst = Vt + (size_t)seg * 262144;
#pragma unroll
    for (int i = 0; i < 32; i += 8)
        dst[(size_t)(e0 + yy + i) * 256 + k0 + xx] = tile[xx][yy + i];
}

// ---------- launch ----------

extern "C" void kernel_launch(void* const* d_in, const int* in_sizes, int n_in,
                              void* d_out, int out_size, void* d_ws, size_t ws_size,
                              hipStream_t stream)
{
    const float* x     = (const float*)d_in[0];
    const float* Wq    = (const float*)d_in[1];
    const float* Wk    = (const float*)d_in[2];
    const float* Wv    = (const float*)d_in[3];
    const float* Wo    = (const float*)d_in[4];
    const float* gamma = (const float*)d_in[5];
    const float* beta  = (const float*)d_in[6];
    float* out = (float*)d_out;

    char* ws = (char*)d_ws;
    bf16_t* Xe   = (bf16_t*)(ws);                  // 8192x1024 bf16   (16 MB)
    bf16_t* Wqkv = (bf16_t*)(ws + (16u  << 20));   // 3072x1024 bf16   ( 6 MB)
    bf16_t* Wob  = (bf16_t*)(ws + (22u  << 20));   // 1024x1024 bf16   ( 2 MB)
    bf16_t* QKV  = (bf16_t*)(ws + (24u  << 20));   // 8192x3072 bf16   (48 MB)
    float*  Smat = (float*) (ws + (72u  << 20));   // 32x256x256 f32   ( 8 MB)
    bf16_t* P    = (bf16_t*)(ws + (80u  << 20));   // 32x256x256 bf16  ( 4 MB)
    bf16_t* Vt   = (bf16_t*)(ws + (84u  << 20));   // 32x1024x256 bf16 (16 MB)
    bf16_t* Y    = (bf16_t*)(ws + (100u << 20));   // 8192x1024 bf16   (16 MB)

    // zero output (odd rows must be zero)
    hipMemsetAsync(d_out, 0, (size_t)out_size * sizeof(float), stream);

    // prep: weight casts + dilated gather
    cast_f32_bf16<<<1024, 256, 0, stream>>>(Wq, Wqkv,           262144);
    cast_f32_bf16<<<1024, 256, 0, stream>>>(Wk, Wqkv + 1048576, 262144);
    cast_f32_bf16<<<1024, 256, 0, stream>>>(Wv, Wqkv + 2097152, 262144);
    cast_f32_bf16<<<1024, 256, 0, stream>>>(Wo, Wob,            262144);
    gather_cast_x<<<8192, 256, 0, stream>>>(x, Xe);

    // QKV projection: [8192,1024] x [3072,1024]^T -> [8192,3072] bf16
    gemm_nt<0><<<dim3(24, 64, 1), 256, 0, stream>>>(
        Xe, Wqkv, QKV, 1024, 1024, 1024, 3072, 0, 0, 0);

    // LayerNorm q,k,v in place
    ln_kernel<<<dim3(8192, 3), 256, 0, stream>>>(QKV, gamma, beta);

    // S = Q K^T per segment: 32 x [256,1024]x[256,1024]^T -> [256,256] f32
    gemm_nt<1><<<dim3(2, 2, 32), 256, 0, stream>>>(
        QKV, QKV + 1024, Smat, 1024, 3072, 3072, 256,
        256L * 3072, 256L * 3072, 65536L);

    // causal softmax -> P bf16
    softmax_kernel<<<8192, 256, 0, stream>>>(Smat, P);

    // V transpose: [256,1024] -> [1024,256] per segment
    transpose_v<<<dim3(32, 8, 32), dim3(32, 8), 0, stream>>>(QKV + 2048, Vt);

    // Y = P V per segment: [256,256] x [1024,256]^T -> [256,1024] bf16
    gemm_nt<0><<<dim3(8, 2, 32), 256, 0, stream>>>(
        P, Vt, Y, 256, 256, 256, 1024,
        65536L, 262144L, 262144L);

    // out = Y Wo^T scattered to even rows of d_out
    gemm_nt<2><<<dim3(8, 64, 1), 256, 0, stream>>>(
        Y, Wob, out, 1024, 1024, 1024, 1024, 0, 0, 0);
}

// Round 2
// 211.443 us; speedup vs baseline: 1.0356x; 1.0356x over previous
//
#include <hip/hip_runtime.h>
#include <stdint.h>

typedef __bf16 bf16_t;
typedef __bf16 bf16x8 __attribute__((ext_vector_type(8)));
typedef __bf16 bf16x4 __attribute__((ext_vector_type(4)));
typedef float  f32x4  __attribute__((ext_vector_type(4)));

// ---------- helpers ----------

__device__ __forceinline__ void gload16(const void* g, void* lds)
{
    __builtin_amdgcn_global_load_lds(
        (__attribute__((address_space(1))) void*)(void*)g,
        (__attribute__((address_space(3))) void*)lds,
        16, 0, 0);
}

__device__ __forceinline__ f32x4 mfma16(bf16x8 a, bf16x8 b, f32x4 c)
{
    return __builtin_amdgcn_mfma_f32_16x16x32_bf16(a, b, c, 0, 0, 0);
}

#define SBAR()   asm volatile("s_barrier" ::: "memory")
#define LGKM0()  asm volatile("s_waitcnt lgkmcnt(0)" ::: "memory")
#define VMCNT(N) asm volatile("s_waitcnt vmcnt(" #N ")" ::: "memory")

// ---------- prep kernels ----------

__global__ __launch_bounds__(256)
void cast_f32_bf16(const float* __restrict__ in, bf16_t* __restrict__ out, int n4)
{
    const int i = blockIdx.x * blockDim.x + threadIdx.x;
    if (i >= n4) return;
    float4 f = *(const float4*)&in[(size_t)i * 4];
    bf16x4 o;
    o[0] = (bf16_t)f.x; o[1] = (bf16_t)f.y; o[2] = (bf16_t)f.z; o[3] = (bf16_t)f.w;
    *(bf16x4*)&out[(size_t)i * 4] = o;
}

__global__ __launch_bounds__(256)
void gather_cast_x(const float* __restrict__ x, bf16_t* __restrict__ Xe)
{
    const int m = blockIdx.x;
    const int b = m >> 11, g = (m >> 8) & 7, j = m & 255;
    const float* src = x + ((size_t)b * 4096 + g * 512 + 2 * j) * 1024;
    bf16_t* dst = Xe + (size_t)m * 1024;
    const int t = threadIdx.x;
    float4 f = *(const float4*)&src[t * 4];
    bf16x4 o;
    o[0] = (bf16_t)f.x; o[1] = (bf16_t)f.y; o[2] = (bf16_t)f.z; o[3] = (bf16_t)f.w;
    *(bf16x4*)&dst[t * 4] = o;
}

// ---------- 256x256 8-phase GEMM: C[M,N] = A[M,K] * B[N,K]^T ----------
// 512 threads = 8 waves (2M x 4N). BK=64. LDS 128KB double-buffered.
// Half-tiles are quadrant-interleaved: A-half mq = rows {wr*128+mq*64+j},
// B-half nq = rows {wc*64+nq*32+j}. Each half is ds_read in exactly one
// phase of its tile, so stage destinations are dead-at-issue.
// LDS swizzle: byte bits(5,6) ^= byte bits(9,10) (involution, both sides).
template<int EPI>   // 0 = store bf16
__global__ __launch_bounds__(512, 2)
void gemm256(const bf16_t* __restrict__ A, const bf16_t* __restrict__ B,
             void* __restrict__ Cv, int K, int lda, int ldb, int ldc)
{
    __shared__ __align__(16) char lds[131072];

    const int tid = threadIdx.x;
    const int w = tid >> 6, lane = tid & 63;
    const int wr = w >> 2, wc = w & 3;
    const int fr = lane & 15, fg = lane >> 4;
    const int bn = blockIdx.x, bm = blockIdx.y;
    const int NT = K >> 6;

    // stage-side fixed offsets (pre-swizzled global source)
    const int d0 = tid, d1 = 512 + tid;
    const int s0 = d0 ^ (((d0 >> 5) & 1) << 1) ^ (((d0 >> 6) & 1) << 2);
    const int s1 = d1 ^ (((d1 >> 5) & 1) << 1) ^ (((d1 >> 6) & 1) << 2);
    const size_t fixA0 = ((size_t)(bm * 256 + (s0 >> 9) * 128 + ((s0 >> 3) & 63)) * lda + (s0 & 7) * 8) * 2;
    const size_t fixA1 = ((size_t)(bm * 256 + (s1 >> 9) * 128 + ((s1 >> 3) & 63)) * lda + (s1 & 7) * 8) * 2;
    const size_t fixB0 = ((size_t)(bn * 256 + (s0 >> 8) * 64 + ((s0 >> 3) & 31)) * ldb + (s0 & 7) * 8) * 2;
    const size_t fixB1 = ((size_t)(bn * 256 + (s1 >> 8) * 64 + ((s1 >> 3) & 31)) * ldb + (s1 & 7) * 8) * 2;
    const size_t mqStep = (size_t)64 * lda * 2;
    const size_t nqStep = (size_t)32 * ldb * 2;
    const char* Ac = (const char*)A;
    const char* Bc = (const char*)B;
    const int ldsW = w * 1024;

#define STAGE(T, ISB, Q) do {                                                     \
    const int _b = ((T) & 1) * 65536 + (ISB) * 32768 + (Q) * 16384 + ldsW;        \
    const char *_g0, *_g1;                                                        \
    if (ISB) { _g0 = Bc + (Q)*nqStep + fixB0 + (size_t)(T)*128;                   \
               _g1 = Bc + (Q)*nqStep + fixB1 + (size_t)(T)*128; }                 \
    else     { _g0 = Ac + (Q)*mqStep + fixA0 + (size_t)(T)*128;                   \
               _g1 = Ac + (Q)*mqStep + fixA1 + (size_t)(T)*128; }                 \
    gload16(_g0, lds + _b);                                                       \
    gload16(_g1, lds + _b + 8192);                                                \
} while (0)

    // read-side bases; swizzle is a thread-constant XOR
    const int abase = wr * 8192 + fr * 128 + fg * 16;
    const int bbase = wc * 4096 + fr * 128 + fg * 16;
    const int flip  = (((fr >> 2) & 1) << 5) | (((fr >> 3) & 1) << 6);

    bf16x8 a[4][2], b0[2][2], b1[2][2];
    f32x4 acc[8][4] = {};

#define LOAD_A(MQ, CB) do {                                                                 \
    _Pragma("unroll") for (int mi = 0; mi < 4; ++mi)                                        \
    _Pragma("unroll") for (int ks = 0; ks < 2; ++ks)                                        \
        a[mi][ks] = *(const bf16x8*)(lds + (CB) + (MQ)*16384 +                              \
                                     ((abase + mi*2048 + ks*64) ^ flip));                   \
} while (0)

#define LOAD_B(REG, NQ, CB) do {                                                            \
    _Pragma("unroll") for (int ni = 0; ni < 2; ++ni)                                        \
    _Pragma("unroll") for (int ks = 0; ks < 2; ++ks)                                        \
        REG[ni][ks] = *(const bf16x8*)(lds + (CB) + 32768 + (NQ)*16384 +                    \
                                       ((bbase + ni*2048 + ks*64) ^ flip));                 \
} while (0)

#define MFMA_Q(MQ, REG, NQ) do {                                                            \
    _Pragma("unroll") for (int mi = 0; mi < 4; ++mi)                                        \
    _Pragma("unroll") for (int ni = 0; ni < 2; ++ni)                                        \
    _Pragma("unroll") for (int ks = 0; ks < 2; ++ks)                                        \
        acc[(MQ)*4+mi][(NQ)*2+ni] =                                                         \
            mfma16(a[mi][ks], REG[ni][ks], acc[(MQ)*4+mi][(NQ)*2+ni]);                      \
} while (0)

    // prologue: tile0 {A0,B0,B1,A1}, vmcnt(4); tile1 {A0,B0,B1}, vmcnt(6)
    STAGE(0, 0, 0); STAGE(0, 1, 0); STAGE(0, 1, 1); STAGE(0, 0, 1);
    VMCNT(4);
    STAGE(1, 0, 0); STAGE(1, 1, 0); STAGE(1, 1, 1);
    VMCNT(6);
    SBAR();

    for (int t = 0; t < NT - 2; ++t) {
        const int cb = (t & 1) * 65536;
        // P1: read A-q0 + B-q0, stage A1(t+1), mfma (0,0)
        LOAD_A(0, cb); LOAD_B(b0, 0, cb);
        STAGE(t + 1, 0, 1);
        SBAR(); LGKM0();
        __builtin_amdgcn_s_setprio(1); MFMA_Q(0, b0, 0); __builtin_amdgcn_s_setprio(0);
        SBAR();
        // P2: read B-q1, stage A0(t+2), mfma (0,1)
        LOAD_B(b1, 1, cb);
        STAGE(t + 2, 0, 0);
        SBAR(); LGKM0();
        __builtin_amdgcn_s_setprio(1); MFMA_Q(0, b1, 1); __builtin_amdgcn_s_setprio(0);
        SBAR();
        // P3: read A-q1, stage B0(t+2), mfma (1,1)
        LOAD_A(1, cb);
        STAGE(t + 2, 1, 0);
        SBAR(); LGKM0();
        __builtin_amdgcn_s_setprio(1); MFMA_Q(1, b1, 1); __builtin_amdgcn_s_setprio(0);
        SBAR();
        // P4: stage B1(t+2), mfma (1,0), counted vmcnt(6)
        STAGE(t + 2, 1, 1);
        SBAR();
        __builtin_amdgcn_s_setprio(1); MFMA_Q(1, b0, 0); __builtin_amdgcn_s_setprio(0);
        VMCNT(6);
        SBAR();
    }

    // tail: stage last missing half, full drain, two unstaged tiles
    STAGE(NT - 1, 0, 1);
    VMCNT(0);
    SBAR();
    for (int t = NT - 2; t < NT; ++t) {
        const int cb = (t & 1) * 65536;
        LOAD_A(0, cb); LOAD_B(b0, 0, cb);
        LGKM0();
        MFMA_Q(0, b0, 0);
        LOAD_B(b1, 1, cb);
        LGKM0();
        MFMA_Q(0, b1, 1);
        LOAD_A(1, cb);
        LGKM0();
        MFMA_Q(1, b1, 1);
        MFMA_Q(1, b0, 0);
    }

#undef STAGE
#undef LOAD_A
#undef LOAD_B
#undef MFMA_Q

    // epilogue: C/D frag layout col=lane&15, row=(lane>>4)*4+r
    const int r0 = bm * 256 + wr * 128 + fg * 4;
    const int c0 = bn * 256 + wc * 64 + fr;
    if constexpr (EPI == 0) {
        bf16_t* C = (bf16_t*)Cv;
#pragma unroll
        for (int mig = 0; mig < 8; ++mig)
#pragma unroll
            for (int nig = 0; nig < 4; ++nig)
#pragma unroll
                for (int r = 0; r < 4; ++r)
                    C[(size_t)(r0 + mig * 16 + r) * ldc + c0 + nig * 16] =
                        (bf16_t)acc[mig][nig][r];
    }
}

// ---------- GEMM: C[M,N] = A[M,K] * B[N,K]^T (128x128 tile, m97 structure) ----------
// EPI: 0 = store bf16, 1 = store f32, 2 = scatter f32 into d_out even rows + zero odd rows.
template<int EPI>
__global__ __launch_bounds__(256)
void gemm_nt(const bf16_t* __restrict__ A, const bf16_t* __restrict__ B,
             void* __restrict__ Cv,
             int K, int lda, int ldb, int ldc,
             long sA, long sB, long sC)
{
    __shared__ __align__(16) bf16_t Asm[128 * 32];
    __shared__ __align__(16) bf16_t Bsm[128 * 32];

    const int tid  = threadIdx.x;
    const int wave = tid >> 6;
    const int lane = tid & 63;
    const int bn = blockIdx.x, bm = blockIdx.y, bz = blockIdx.z;
    const int wr = wave >> 1, wc = wave & 1;

    const bf16_t* Ab = A + (long)bz * sA;
    const bf16_t* Bb = B + (long)bz * sB;

    const int srow = tid >> 2;
    const int scol = (tid & 3) * 8;
    const bf16_t* a0 = Ab + (size_t)(bm * 128 + srow) * lda + scol;
    const bf16_t* a1 = a0 + (size_t)64 * lda;
    const bf16_t* b0 = Bb + (size_t)(bn * 128 + srow) * ldb + scol;
    const bf16_t* b1 = b0 + (size_t)64 * ldb;
    char* ldsA = (char*)Asm + wave * 1024;
    char* ldsB = (char*)Bsm + wave * 1024;

    f32x4 acc[4][4] = {};

    const int frow = lane & 15;
    const int fk   = (lane >> 4) * 8;

    for (int k0 = 0; k0 < K; k0 += 32) {
        gload16(a0, ldsA);
        gload16(a1, ldsA + 4096);
        gload16(b0, ldsB);
        gload16(b1, ldsB + 4096);
        a0 += 32; a1 += 32; b0 += 32; b1 += 32;
        __syncthreads();

        bf16x8 af[4], bfr[4];
#pragma unroll
        for (int mi = 0; mi < 4; ++mi)
            af[mi] = *(const bf16x8*)&Asm[(size_t)(wr * 64 + mi * 16 + frow) * 32 + fk];
#pragma unroll
        for (int ni = 0; ni < 4; ++ni)
            bfr[ni] = *(const bf16x8*)&Bsm[(size_t)(wc * 64 + ni * 16 + frow) * 32 + fk];
#pragma unroll
        for (int mi = 0; mi < 4; ++mi)
#pragma unroll
            for (int ni = 0; ni < 4; ++ni)
                acc[mi][ni] = mfma16(af[mi], bfr[ni], acc[mi][ni]);
        __syncthreads();
    }

    const int row0 = bm * 128 + wr * 64 + (lane >> 4) * 4;
    const int col0 = bn * 128 + wc * 64 + frow;

    if constexpr (EPI == 0) {
        bf16_t* C = (bf16_t*)Cv + (long)bz * sC;
#pragma unroll
        for (int mi = 0; mi < 4; ++mi)
#pragma unroll
            for (int ni = 0; ni < 4; ++ni)
#pragma unroll
                for (int r = 0; r < 4; ++r)
                    C[(size_t)(row0 + mi * 16 + r) * ldc + col0 + ni * 16] =
                        (bf16_t)acc[mi][ni][r];
    } else if constexpr (EPI == 1) {
        float* C = (float*)Cv + (long)bz * sC;
#pragma unroll
        for (int mi = 0; mi < 4; ++mi)
#pragma unroll
            for (int ni = 0; ni < 4; ++ni)
#pragma unroll
                for (int r = 0; r < 4; ++r)
                    C[(size_t)(row0 + mi * 16 + r) * ldc + col0 + ni * 16] =
                        acc[mi][ni][r];
    } else {
        // scatter even rows, zero odd rows (replaces the 64MB memset)
        float* C = (float*)Cv;
#pragma unroll
        for (int mi = 0; mi < 4; ++mi)
#pragma unroll
            for (int ni = 0; ni < 4; ++ni)
#pragma unroll
                for (int r = 0; r < 4; ++r) {
                    const int m  = row0 + mi * 16 + r;
                    const int gr = ((m >> 11) << 12) | (((m >> 8) & 7) << 9) | ((m & 255) << 1);
                    C[(size_t)gr * 1024 + col0 + ni * 16]       = acc[mi][ni][r];
                    C[(size_t)(gr + 1) * 1024 + col0 + ni * 16] = 0.0f;
                }
    }
}

// ---------- LayerNorm (in place on bf16 QKV rows, D=1024) ----------
__global__ __launch_bounds__(256)
void ln_kernel(bf16_t* __restrict__ qkv,
               const float* __restrict__ gamma, const float* __restrict__ beta)
{
    const int row = blockIdx.x;
    const int which = blockIdx.y;
    bf16_t* p = qkv + (size_t)row * 3072 + which * 1024;
    const int t = threadIdx.x;

    bf16x4 v = *(const bf16x4*)&p[t * 4];
    float f[4];
    float s = 0.f, ss = 0.f;
#pragma unroll
    for (int i = 0; i < 4; ++i) { f[i] = (float)v[i]; s += f[i]; ss += f[i] * f[i]; }
#pragma unroll
    for (int o = 32; o; o >>= 1) { s += __shfl_xor(s, o); ss += __shfl_xor(ss, o); }

    __shared__ float rs_[4], rss_[4];
    const int wave = t >> 6, lane = t & 63;
    if (lane == 0) { rs_[wave] = s; rss_[wave] = ss; }
    __syncthreads();
    s  = rs_[0] + rs_[1] + rs_[2] + rs_[3];
    ss = rss_[0] + rss_[1] + rss_[2] + rss_[3];

    const float mu   = s * (1.f / 1024.f);
    const float var  = ss * (1.f / 1024.f) - mu * mu;
    const float rstd = rsqrtf(var + 1e-5f);

    bf16x4 o;
#pragma unroll
    for (int i = 0; i < 4; ++i) {
        const int c = t * 4 + i;
        o[i] = (bf16_t)((f[i] - mu) * rstd * gamma[c] + beta[c]);
    }
    *(bf16x4*)&p[t * 4] = o;
}

// ---------- causal softmax: S[32*256][256] f32 -> P bf16 ----------
__global__ __launch_bounds__(256)
void softmax_kernel(const float* __restrict__ S, bf16_t* __restrict__ P)
{
    const int q = blockIdx.x & 255;
    const size_t base = (size_t)blockIdx.x * 256;
    const int c = threadIdx.x;
    const bool ok = (c <= q);

    float v = ok ? S[base + c] * (1.f / 32.f) : -3.0e38f;
    float m = v;
#pragma unroll
    for (int o = 32; o; o >>= 1) m = fmaxf(m, __shfl_xor(m, o));

    __shared__ float rm[4], rsum[4];
    const int wave = c >> 6, lane = c & 63;
    if (lane == 0) rm[wave] = m;
    __syncthreads();
    m = fmaxf(fmaxf(rm[0], rm[1]), fmaxf(rm[2], rm[3]));

    float e = ok ? __expf(v - m) : 0.f;
    float s = e;
#pragma unroll
    for (int o = 32; o; o >>= 1) s += __shfl_xor(s, o);
    if (lane == 0) rsum[wave] = s;
    __syncthreads();
    s = rsum[0] + rsum[1] + rsum[2] + rsum[3];

    P[base + c] = (bf16_t)(e / s);
}

// ---------- V transpose per segment ----------
__global__ __launch_bounds__(256)
void transpose_v(const bf16_t* __restrict__ Vn, bf16_t* __restrict__ Vt)
{
    __shared__ bf16_t tile[32][33];
    const int seg = blockIdx.z;
    const int e0 = blockIdx.x * 32, k0 = blockIdx.y * 32;
    const int xx = threadIdx.x, yy = threadIdx.y;
    const bf16_t* src = Vn + (size_t)seg * 256 * 3072;
#pragma unroll
    for (int i = 0; i < 32; i += 8)
        tile[yy + i][xx] = src[(size_t)(k0 + yy + i) * 3072 + e0 + xx];
    __syncthreads();
    bf16_t* dst = Vt + (size_t)seg * 262144;
#pragma unroll
    for (int i = 0; i < 32; i += 8)
        dst[(size_t)(e0 + yy + i) * 256 + k0 + xx] = tile[xx][yy + i];
}

// ---------- launch ----------

extern "C" void kernel_launch(void* const* d_in, const int* in_sizes, int n_in,
                              void* d_out, int out_size, void* d_ws, size_t ws_size,
                              hipStream_t stream)
{
    const float* x     = (const float*)d_in[0];
    const float* Wq    = (const float*)d_in[1];
    const float* Wk    = (const float*)d_in[2];
    const float* Wv    = (const float*)d_in[3];
    const float* Wo    = (const float*)d_in[4];
    const float* gamma = (const float*)d_in[5];
    const float* beta  = (const float*)d_in[6];
    float* out = (float*)d_out;

    char* ws = (char*)d_ws;
    bf16_t* Xe   = (bf16_t*)(ws);                  // 8192x1024 bf16   (16 MB)
    bf16_t* Wqkv = (bf16_t*)(ws + (16u  << 20));   // 3072x1024 bf16   ( 6 MB)
    bf16_t* Wob  = (bf16_t*)(ws + (22u  << 20));   // 1024x1024 bf16   ( 2 MB)
    bf16_t* QKV  = (bf16_t*)(ws + (24u  << 20));   // 8192x3072 bf16   (48 MB)
    float*  Smat = (float*) (ws + (72u  << 20));   // 32x256x256 f32   ( 8 MB)
    bf16_t* P    = (bf16_t*)(ws + (80u  << 20));   // 32x256x256 bf16  ( 4 MB)
    bf16_t* Vt   = (bf16_t*)(ws + (84u  << 20));   // 32x1024x256 bf16 (16 MB)
    bf16_t* Y    = (bf16_t*)(ws + (100u << 20));   // 8192x1024 bf16   (16 MB)

    // prep: weight casts + dilated gather
    cast_f32_bf16<<<1024, 256, 0, stream>>>(Wq, Wqkv,           262144);
    cast_f32_bf16<<<1024, 256, 0, stream>>>(Wk, Wqkv + 1048576, 262144);
    cast_f32_bf16<<<1024, 256, 0, stream>>>(Wv, Wqkv + 2097152, 262144);
    cast_f32_bf16<<<1024, 256, 0, stream>>>(Wo, Wob,            262144);
    gather_cast_x<<<8192, 256, 0, stream>>>(x, Xe);

    // QKV projection: [8192,1024] x [3072,1024]^T -> [8192,3072] bf16 (8-phase 256^2)
    gemm256<0><<<dim3(12, 32), 512, 0, stream>>>(Xe, Wqkv, QKV, 1024, 1024, 1024, 3072);

    // LayerNorm q,k,v in place
    ln_kernel<<<dim3(8192, 3), 256, 0, stream>>>(QKV, gamma, beta);

    // S = Q K^T per segment
    gemm_nt<1><<<dim3(2, 2, 32), 256, 0, stream>>>(
        QKV, QKV + 1024, Smat, 1024, 3072, 3072, 256,
        256L * 3072, 256L * 3072, 65536L);

    // causal softmax -> P bf16
    softmax_kernel<<<8192, 256, 0, stream>>>(Smat, P);

    // V transpose
    transpose_v<<<dim3(32, 8, 32), dim3(32, 8), 0, stream>>>(QKV + 2048, Vt);

    // Y = P V per segment
    gemm_nt<0><<<dim3(8, 2, 32), 256, 0, stream>>>(
        P, Vt, Y, 256, 256, 256, 1024,
        65536L, 262144L, 262144L);

    // out = Y Wo^T scattered to even rows of d_out, odd rows zeroed
    gemm_nt<2><<<dim3(8, 64, 1), 256, 0, stream>>>(
        Y, Wob, out, 1024, 1024, 1024, 1024, 0, 0, 0);
}